// Round 1
// baseline (716.502 us; speedup 1.0000x reference)
//
#include <hip/hip_runtime.h>
#include <math.h>

#define VOCAB 32000
#define NV4   (VOCAB / 4)   // 8000 float4 per token row
#define BLK   256
#define SEQ   2048
#define IGNORE_IDX (-100)

// Online-softmax merge of two states (m, s, t):
//   s = sum exp(x - m),  t = sum exp(x - m) * (x - m)
__device__ inline void merge_state(float& m, float& s, float& t,
                                   float om, float os, float ot) {
    float mm = fmaxf(m, om);
    float ca = __expf(m - mm);
    float cb = __expf(om - mm);
    t = ca * (t + (m - mm) * s) + cb * (ot + (om - mm) * os);
    s = ca * s + cb * os;
    m = mm;
}

__global__ void init_ws_kernel(float* ws) {
    if (threadIdx.x < 8) ws[threadIdx.x] = 0.0f;
}

__global__ __launch_bounds__(BLK)
void ce_metrics_kernel(const float* __restrict__ logits,
                       const int* __restrict__ labels,
                       float* __restrict__ out,   // [0]=loss, [1..N]=ce, [N+1..2N]=entropy, [2N+1..2N+3]=accs
                       float* __restrict__ ws,    // [0]=ce_sum [1]=n_valid [2..4]=hits(1,5,20)
                       int N)                     // N = B*S tokens
{
    const int n = blockIdx.x;
    const int pos = n % SEQ;

    float* ce_out  = out + 1;
    float* ent_out = out + 1 + N;

    // shifted label: labels[b, pos+1], last position of each sequence invalid
    int label = (pos < SEQ - 1) ? labels[n + 1] : IGNORE_IDX;

    if (label < 0) {
        if (threadIdx.x == 0) { ce_out[n] = 0.0f; ent_out[n] = 0.0f; }
        return;
    }

    const float* __restrict__ row = logits + (size_t)n * VOCAB;
    const float x_label = row[label];            // same addr across block -> broadcast
    const float4* __restrict__ row4 = (const float4*)row;

    float m = -3.402823466e38f;   // -FLT_MAX (not -inf: keeps m-x finite)
    float s = 0.0f, t = 0.0f;
    int cgt = 0;   // count of logits strictly greater than x_label
    int ceq = 0;   // ties with lower vocab index (top_k tiebreak)

    for (int i = threadIdx.x; i < NV4; i += BLK) {
        float4 x4 = row4[i];
        const float xs[4] = {x4.x, x4.y, x4.z, x4.w};
        #pragma unroll
        for (int j = 0; j < 4; ++j) {
            float x = xs[j];
            if (x > m) {
                float c = __expf(m - x);         // exp(-huge) -> 0 on first iter
                t = c * (t + (m - x) * s);       // s==0 first iter -> finite
                s = c * s + 1.0f;                // new element contributes exp(0)=1
                m = x;
            } else {
                float d = x - m;
                float e = __expf(d);
                s += e;
                t += e * d;
            }
            cgt += (x > x_label) ? 1 : 0;
            ceq += (x == x_label && (4 * i + j) < label) ? 1 : 0;
        }
    }

    // wave (64-lane) butterfly reduction
    #pragma unroll
    for (int mask = 32; mask > 0; mask >>= 1) {
        float om = __shfl_xor(m, mask);
        float os = __shfl_xor(s, mask);
        float ot = __shfl_xor(t, mask);
        cgt += __shfl_xor(cgt, mask);
        ceq += __shfl_xor(ceq, mask);
        merge_state(m, s, t, om, os, ot);
    }

    // cross-wave reduction through LDS (BLK/64 = 4 waves)
    __shared__ float sm[4], ss[4], st[4];
    __shared__ int sgt[4], seq_[4];
    const int wid  = threadIdx.x >> 6;
    const int lane = threadIdx.x & 63;
    if (lane == 0) { sm[wid] = m; ss[wid] = s; st[wid] = t; sgt[wid] = cgt; seq_[wid] = ceq; }
    __syncthreads();

    if (threadIdx.x == 0) {
        m = sm[0]; s = ss[0]; t = st[0]; cgt = sgt[0]; ceq = seq_[0];
        #pragma unroll
        for (int w = 1; w < 4; ++w) {
            merge_state(m, s, t, sm[w], ss[w], st[w]);
            cgt += sgt[w];
            ceq += seq_[w];
        }
        float logs = logf(s);
        float ce   = m + logs - x_label;   // -(x_label - m - log s)
        float ent  = logs - t / s;         // -(t/s) + log s
        ce_out[n]  = ce;
        ent_out[n] = ent;

        int rank = cgt + ceq;              // label in top-k iff rank < k
        atomicAdd(&ws[0], ce);
        atomicAdd(&ws[1], 1.0f);
        if (rank < 1)  atomicAdd(&ws[2], 1.0f);
        if (rank < 5)  atomicAdd(&ws[3], 1.0f);
        if (rank < 20) atomicAdd(&ws[4], 1.0f);
    }
}

__global__ void finalize_kernel(const float* __restrict__ ws,
                                float* __restrict__ out, int N) {
    if (threadIdx.x == 0) {
        float nv = ws[1];
        out[0]         = ws[0] / nv;   // loss
        out[1 + 2 * N]     = ws[2] / nv;   // acc@1
        out[1 + 2 * N + 1] = ws[3] / nv;   // acc@5
        out[1 + 2 * N + 2] = ws[4] / nv;   // acc@20
    }
}

extern "C" void kernel_launch(void* const* d_in, const int* in_sizes, int n_in,
                              void* d_out, int out_size, void* d_ws, size_t ws_size,
                              hipStream_t stream) {
    const float* logits = (const float*)d_in[0];
    const int*   labels = (const int*)d_in[1];
    float* out = (float*)d_out;
    float* ws  = (float*)d_ws;

    const int N = in_sizes[1];   // B*S tokens (4096)

    init_ws_kernel<<<1, 64, 0, stream>>>(ws);
    ce_metrics_kernel<<<N, BLK, 0, stream>>>(logits, labels, out, ws, N);
    finalize_kernel<<<1, 64, 0, stream>>>(ws, out, N);
}

// Round 2
// 679.658 us; speedup vs baseline: 1.0542x; 1.0542x over previous
//
#include <hip/hip_runtime.h>
#include <math.h>

#define VOCAB 32000
#define NV4   (VOCAB / 4)     // 8000 float4 per token row
#define SEQ   2048
#define ITERS (NV4 / 64)      // 125 float4-iterations per 64-lane wave
#define IGNORE_IDX (-100)

// Online-softmax state: m = running max, s = sum exp(x-m), t = sum exp(x-m)*(x-m)
// Branchless merge; deltas clamped so (-inf)*0 never produces NaN.
__device__ inline void merge_state(float& m, float& s, float& t,
                                   float om, float os, float ot) {
    float mm = fmaxf(m, om);
    float da = fmaxf(m - mm, -64.0f);
    float db = fmaxf(om - mm, -64.0f);
    float ca = __expf(da);
    float cb = __expf(db);
    t = ca * (t + da * s) + cb * (ot + db * os);
    s = ca * s + cb * os;
    m = mm;
}

__global__ __launch_bounds__(256)
void ce_metrics_kernel(const float* __restrict__ logits,
                       const int* __restrict__ labels,
                       float* __restrict__ out,   // [0]=loss, [1..N]=ce, [1+N..2N]=entropy, then 3 accs
                       float* __restrict__ ws,    // per-token rank (-1 = invalid)
                       int N)
{
    const int token = (blockIdx.x << 2) + (threadIdx.x >> 6);  // one wave per token
    const int lane  = threadIdx.x & 63;
    if (token >= N) return;

    float* ce_out  = out + 1;
    float* ent_out = out + 1 + N;

    const int pos = token & (SEQ - 1);
    const int label = (pos < SEQ - 1) ? labels[token + 1] : IGNORE_IDX;

    if (label < 0) {
        if (lane == 0) { ce_out[token] = 0.0f; ent_out[token] = 0.0f; ws[token] = -1.0f; }
        return;
    }

    const float* __restrict__ row = logits + (size_t)token * VOCAB;
    const float xl = row[label];               // same addr across wave -> broadcast
    const float4* __restrict__ row4 = (const float4*)row;

    float m = -3.402823466e38f, s = 0.0f, t = 0.0f;
    int cgt = 0;   // #{x > xl}
    int ceq = 0;   // #{x == xl with lower vocab index}  (top_k tiebreak)

    #pragma unroll 5
    for (int it = 0; it < ITERS; ++it) {
        const int i4 = it * 64 + lane;         // contiguous 1 KB per wave-iter
        float4 x4 = row4[i4];

        // chunk max, single rescale per 4 elements
        float m4 = fmaxf(fmaxf(x4.x, x4.y), fmaxf(x4.z, x4.w));
        float nm = fmaxf(m, m4);
        float d1 = fmaxf(m - nm, -64.0f);      // clamp: first iter gives exp(-64)*0 = 0, no NaN
        float c  = __expf(d1);
        float cs = c * s;
        t = fmaf(d1, cs, c * t);
        s = cs;
        m = nm;

        float dx = x4.x - m, dy = x4.y - m, dz = x4.z - m, dw = x4.w - m;
        float ex = __expf(dx), ey = __expf(dy), ez = __expf(dz), ew = __expf(dw);
        s += (ex + ey) + (ez + ew);
        t = fmaf(ex, dx, t); t = fmaf(ey, dy, t);
        t = fmaf(ez, dz, t); t = fmaf(ew, dw, t);

        const int base = i4 << 2;
        cgt += (x4.x > xl) + (x4.y > xl) + (x4.z > xl) + (x4.w > xl);
        ceq += ((x4.x == xl) & (base     < label))
             + ((x4.y == xl) & (base + 1 < label))
             + ((x4.z == xl) & (base + 2 < label))
             + ((x4.w == xl) & (base + 3 < label));
    }

    // 64-lane butterfly reduction, no LDS
    #pragma unroll
    for (int mask = 32; mask; mask >>= 1) {
        float om = __shfl_xor(m, mask);
        float os = __shfl_xor(s, mask);
        float ot = __shfl_xor(t, mask);
        cgt += __shfl_xor(cgt, mask);
        ceq += __shfl_xor(ceq, mask);
        merge_state(m, s, t, om, os, ot);
    }

    if (lane == 0) {
        float logs = logf(s);
        ce_out[token]  = m + logs - xl;
        ent_out[token] = logs - t / s;
        ws[token] = (float)(cgt + ceq);        // rank; label in top-k iff rank < k
    }
}

__global__ __launch_bounds__(256)
void finalize_kernel(const float* __restrict__ ws,
                     float* __restrict__ out, int N)
{
    const float* ce = out + 1;
    float ce_sum = 0.f, nv = 0.f, h1 = 0.f, h5 = 0.f, h20 = 0.f;
    for (int i = threadIdx.x; i < N; i += 256) {
        float r = ws[i];
        if (r >= 0.f) {
            nv     += 1.f;
            ce_sum += ce[i];
            h1  += (r < 1.f)  ? 1.f : 0.f;
            h5  += (r < 5.f)  ? 1.f : 0.f;
            h20 += (r < 20.f) ? 1.f : 0.f;
        }
    }
    #pragma unroll
    for (int mask = 32; mask; mask >>= 1) {
        ce_sum += __shfl_xor(ce_sum, mask);
        nv     += __shfl_xor(nv, mask);
        h1     += __shfl_xor(h1, mask);
        h5     += __shfl_xor(h5, mask);
        h20    += __shfl_xor(h20, mask);
    }
    __shared__ float red[5][4];
    const int wid = threadIdx.x >> 6, lane = threadIdx.x & 63;
    if (lane == 0) {
        red[0][wid] = ce_sum; red[1][wid] = nv;
        red[2][wid] = h1; red[3][wid] = h5; red[4][wid] = h20;
    }
    __syncthreads();
    if (threadIdx.x == 0) {
        ce_sum = red[0][0] + red[0][1] + red[0][2] + red[0][3];
        nv     = red[1][0] + red[1][1] + red[1][2] + red[1][3];
        h1     = red[2][0] + red[2][1] + red[2][2] + red[2][3];
        h5     = red[3][0] + red[3][1] + red[3][2] + red[3][3];
        h20    = red[4][0] + red[4][1] + red[4][2] + red[4][3];
        out[0]         = ce_sum / nv;
        out[1 + 2*N]     = h1  / nv;
        out[1 + 2*N + 1] = h5  / nv;
        out[1 + 2*N + 2] = h20 / nv;
    }
}

extern "C" void kernel_launch(void* const* d_in, const int* in_sizes, int n_in,
                              void* d_out, int out_size, void* d_ws, size_t ws_size,
                              hipStream_t stream) {
    const float* logits = (const float*)d_in[0];
    const int*   labels = (const int*)d_in[1];
    float* out = (float*)d_out;
    float* ws  = (float*)d_ws;

    const int N = in_sizes[1];   // B*S tokens (4096)

    ce_metrics_kernel<<<(N + 3) / 4, 256, 0, stream>>>(logits, labels, out, ws, N);
    finalize_kernel<<<1, 256, 0, stream>>>(ws, out, N);
}